// Round 1
// baseline (261.699 us; speedup 1.0000x reference)
//
#include <hip/hip_runtime.h>
#include <hip/hip_bf16.h>

// Problem constants (B,T,H,W,D = 32,16,32,32,64)
#define B_   32
#define T_   16
#define H_   32
#define W_   32
#define D_   64
#define N_   16384          // T*H*W
#define KPT  64             // keys per thread in select kernel (N_/256)
#define BLK  256

// ---------------------------------------------------------------------------
// K1: per-row gumbel+marg keys, exact top-k threshold (bitwise binary search
// on order-preserving uint32 keys), visible mask written as 0/1 floats.
// One block per row b. Keys live entirely in registers (64 per thread).
// ---------------------------------------------------------------------------
__global__ __launch_bounds__(BLK, 1) void select_kernel(
    const float* __restrict__ u_g,
    const float* __restrict__ logp_t,
    const float* __restrict__ logp_h,
    const float* __restrict__ logp_w,
    const float* __restrict__ u_k,
    float* __restrict__ vis_out,     // d_out + 1, [B_*N_] floats (0/1)
    double* __restrict__ misc)       // [0]=loss accumulator, [1..32]=1/rc_b
{
    const int b   = blockIdx.x;
    const int tid = threadIdx.x;

    __shared__ float s_lt[T_], s_lh[H_], s_lw[W_];
    __shared__ int   s_part[4];
    __shared__ int   s_tot;
    __shared__ int   s_cnt;
    __shared__ int   s_list[2048];   // rare tie-path index list

    if (tid < T_) s_lt[tid] = logp_t[b*T_ + tid];
    if (tid < H_) s_lh[tid] = logp_h[b*H_ + tid];
    if (tid < W_) s_lw[tid] = logp_w[b*W_ + tid];
    if (b == 0 && tid == 0) misc[0] = 0.0;   // zero the loss accumulator
    __syncthreads();

    // ---- compute keys (order-preserving uint32 of ws) ----
    unsigned keys[KPT];
#pragma unroll
    for (int i = 0; i < KPT; ++i) {
        int   n = i*BLK + tid;
        float u = u_g[b*N_ + n];
        // match numpy stepwise fp32: log, negate, log, negate
        float g = -logf(-logf(u));
        int t = n >> 10;            // / (H_*W_)
        int h = (n >> 5) & 31;
        int w = n & 31;
        float wsv = g + ((s_lt[t] + s_lh[h]) + s_lw[w]);  // same add order as ref
        unsigned bits = __float_as_uint(wsv);
        keys[i] = (bits & 0x80000000u) ? ~bits : (bits | 0x80000000u);
    }

    // ---- k for this row (np.linspace + fp32 mod/trunc semantics) ----
    float u0    = u_k[0];
    float strat = (b == B_-1) ? 1.0f : (float)((double)b * (1.0/31.0));
    float rate  = fmodf(u0 + strat, 1.0f);
    int   k     = (int)(16384.0f * rate);
    k = k < 1 ? 1 : (k > N_-1 ? N_-1 : k);

    // ---- bitwise binary search for max thr with count(keys >= thr) >= k ----
    unsigned thr = 0u;
    for (int bit = 31; bit >= 0; --bit) {
        unsigned cand = thr | (1u << bit);
        int c = 0;
#pragma unroll
        for (int i = 0; i < KPT; ++i) c += (keys[i] >= cand) ? 1 : 0;
        for (int off = 32; off > 0; off >>= 1) c += __shfl_down(c, off);
        if ((tid & 63) == 0) s_part[tid >> 6] = c;
        __syncthreads();
        if (tid == 0) s_tot = s_part[0] + s_part[1] + s_part[2] + s_part[3];
        __syncthreads();
        if (s_tot >= k) thr = cand;
    }

    // ---- count strictly-greater and equal ----
    {
        int cg = 0, ce = 0;
#pragma unroll
        for (int i = 0; i < KPT; ++i) {
            cg += (keys[i] >  thr) ? 1 : 0;
            ce += (keys[i] == thr) ? 1 : 0;
        }
        int packed = cg | (ce << 16);   // per-field totals <= 16384, no overflow
        for (int off = 32; off > 0; off >>= 1) packed += __shfl_down(packed, off);
        if ((tid & 63) == 0) s_part[tid >> 6] = packed;
        __syncthreads();
        if (tid == 0) s_tot = s_part[0] + s_part[1] + s_part[2] + s_part[3];
        __syncthreads();
    }
    const int tot      = s_tot;
    const int count_gt = tot & 0xffff;
    const int count_eq = tot >> 16;
    const int need_eq  = k - count_gt;          // >=1 and <= count_eq by construction

    // ---- rare tie path: need index-ordered selection among equal keys ----
    const bool rare = (count_eq != need_eq);
    if (tid == 0) s_cnt = 0;
    __syncthreads();
    if (rare && count_eq <= 2048) {
#pragma unroll
        for (int i = 0; i < KPT; ++i) {
            if (keys[i] == thr) {
                int slot = atomicAdd(&s_cnt, 1);
                s_list[slot] = i*BLK + tid;
            }
        }
    }
    __syncthreads();

    // ---- write visible mask (coalesced) ----
#pragma unroll
    for (int i = 0; i < KPT; ++i) {
        int n = i*BLK + tid;
        float v;
        if (keys[i] > thr) {
            v = 1.0f;
        } else if (keys[i] == thr) {
            if (!rare || count_eq > 2048) {
                v = 1.0f;                       // all equals visible (common case)
            } else {
                int r = 0;
                for (int j = 0; j < count_eq; ++j) r += (s_list[j] < n) ? 1 : 0;
                v = (r < need_eq) ? 1.0f : 0.0f; // first need_eq by index visible
            }
        } else {
            v = 0.0f;
        }
        vis_out[b*N_ + n] = v;
    }

    if (tid == 0) {
        float rc = (float)(N_ - k) / (float)N_;  // exact: power-of-2 division
        misc[1 + b] = 1.0 / (double)rc;
    }
}

// ---------------------------------------------------------------------------
// K2: sum score over masked tokens, scaled by 1/rc_b. 16-lane groups read one
// token (64 floats = 16x float4, 256B contiguous) only when masked.
// ---------------------------------------------------------------------------
__global__ __launch_bounds__(BLK, 1) void loss_kernel(
    const float*  __restrict__ score,
    const float*  __restrict__ vis,
    const double* __restrict__ misc,   // [1..32] = 1/rc_b
    double*       __restrict__ acc)    // &misc[0]
{
    const int tid  = threadIdx.x;
    const int lane = tid & 63;
    const int grp  = lane >> 4;        // 4 groups of 16 lanes per wave
    const int sub  = lane & 15;
    const int gw   = (blockIdx.x * BLK + tid) >> 6;                  // global wave
    const int totalGroups = ((gridDim.x * BLK) >> 6) << 2;           // waves*4

    double a = 0.0;
    for (int token = gw*4 + grp; token < B_*N_; token += totalGroups) {
        float v = vis[token];
        if (v == 0.0f) {               // masked -> contributes to loss
            const float4* p = (const float4*)(score + (size_t)token * D_);
            float4 x = p[sub];
            float s = (x.x + x.y) + (x.z + x.w);
            s += __shfl_xor(s, 1);
            s += __shfl_xor(s, 2);
            s += __shfl_xor(s, 4);
            s += __shfl_xor(s, 8);
            if (sub == 0) {
                int b = token >> 14;   // token / N_
                a += (double)s * misc[1 + b];
            }
        }
    }

    // block reduction of doubles
    for (int off = 32; off > 0; off >>= 1) a += __shfl_down(a, off);
    __shared__ double s_a[4];
    if (lane == 0) s_a[tid >> 6] = a;
    __syncthreads();
    if (tid == 0) {
        double t = s_a[0] + s_a[1] + s_a[2] + s_a[3];
        atomicAdd(acc, t);
    }
}

// ---------------------------------------------------------------------------
// K3: finalize loss = acc / (B*N*D)
// ---------------------------------------------------------------------------
__global__ void finalize_kernel(const double* __restrict__ acc,
                                float* __restrict__ out)
{
    out[0] = (float)(acc[0] / 33554432.0);   // B_*N_*D_ = 2^25
}

extern "C" void kernel_launch(void* const* d_in, const int* in_sizes, int n_in,
                              void* d_out, int out_size, void* d_ws, size_t ws_size,
                              hipStream_t stream) {
    const float* u_g    = (const float*)d_in[0];
    const float* logp_t = (const float*)d_in[1];
    const float* logp_h = (const float*)d_in[2];
    const float* logp_w = (const float*)d_in[3];
    const float* u_k    = (const float*)d_in[4];
    const float* score  = (const float*)d_in[5];

    float*  out  = (float*)d_out;      // [0]=loss, [1..B*N]=visible (0/1)
    double* misc = (double*)d_ws;      // [0]=acc, [1..32]=1/rc_b

    select_kernel<<<B_, BLK, 0, stream>>>(u_g, logp_t, logp_h, logp_w, u_k,
                                          out + 1, misc);
    loss_kernel<<<2048, BLK, 0, stream>>>(score, out + 1, misc, misc);
    finalize_kernel<<<1, 1, 0, stream>>>(misc, out);
}